// Round 1
// baseline (702.818 us; speedup 1.0000x reference)
//
#include <hip/hip_runtime.h>
#include <math.h>

#define D_MODEL 2048
#define NEXP    64
#define NROWS   32768
#define BM      64                 // rows per block (= lanes per wave)
#define BK      64                 // k per chunk
#define NCHUNK  (D_MODEL / BK)     // 32
#define NGRAN   (BK / 4)           // 16 granules (16B) per chunk row

typedef float f32x8 __attribute__((ext_vector_type(8)));

// async global->LDS, 16B per lane; LDS dest = wave-uniform base + lane*16
__device__ __forceinline__ void stage16(const float* gsrc, void* lds_base) {
    __builtin_amdgcn_global_load_lds(
        (const __attribute__((address_space(1))) void*)gsrc,
        (__attribute__((address_space(3))) void*)lds_base,
        16, 0, 0);
}

// Mapping: block = 512 threads = 8 waves. Wave w owns experts [8w, 8w+8).
// Lane l owns row r0+l. W is wave-uniform -> SGPRs via scalar loads (no LDS,
// no VALU). x staged in LDS granule-major: xsg[buf][q][row] (16B each), read
// as 1 ds_read_b128 per 4 k per lane -> LDS demand ~41us < 54.6us FMA floor.
#define ROW_FMA(J, WV)                           \
    acc[J] = fmaf(WV[0], xa.x, acc[J]);          \
    acc[J] = fmaf(WV[1], xa.y, acc[J]);          \
    acc[J] = fmaf(WV[2], xa.z, acc[J]);          \
    acc[J] = fmaf(WV[3], xa.w, acc[J]);          \
    acc[J] = fmaf(WV[4], xb.x, acc[J]);          \
    acc[J] = fmaf(WV[5], xb.y, acc[J]);          \
    acc[J] = fmaf(WV[6], xb.z, acc[J]);          \
    acc[J] = fmaf(WV[7], xb.w, acc[J]);

__global__ __launch_bounds__(512, 4) void router_kernel(
    const float* __restrict__ x,      // [NROWS, D_MODEL]
    const float* __restrict__ gw,     // [NEXP, D_MODEL]
    const float* __restrict__ bias,   // [NEXP]
    float* __restrict__ out)          // [NROWS*2 weights][NROWS*2 idx-as-float]
{
    // LDS: double-buffered x chunk, granule-major. 2*16*64*16B = 32 KB.
    __shared__ alignas(16) float4 xsg[2][NGRAN][BM];
    // 68-float row stride: rows stay 16B-aligned, stride%32 banks != 0.
    __shared__ alignas(16) float  logits[BM][68];

    const int t    = threadIdx.x;
    const int lane = t & 63;
    const int w    = __builtin_amdgcn_readfirstlane(t >> 6);   // wave id 0..7
    const int r0   = blockIdx.x * BM;

    const float* wp   = gw + (size_t)(w * 8) * D_MODEL;  // wave's 8 experts
    const float* xrow = x  + (size_t)(r0 + lane) * D_MODEL;
    const int q0 = w * 2;            // this wave stages granules q0, q0+1

    float acc[8];
#pragma unroll
    for (int j = 0; j < 8; ++j) acc[j] = 0.f;

    // prologue: stage chunk 0 into buffer 0 (8 waves x 2 granules = 16)
    stage16(xrow + q0 * 4,     &xsg[0][q0][0]);
    stage16(xrow + q0 * 4 + 4, &xsg[0][q0 + 1][0]);
    __syncthreads();   // barrier drain (vmcnt 0) completes the stage

    for (int c = 0; c < NCHUNK; ++c) {
        const int cur = c & 1;
        // issue next chunk's async loads; they complete under this chunk's
        // compute and are drained by the end-of-iteration barrier.
        if (c + 1 < NCHUNK) {
            const int kb2 = (c + 1) * BK;
            stage16(xrow + kb2 + q0 * 4,     &xsg[cur ^ 1][q0][0]);
            stage16(xrow + kb2 + q0 * 4 + 4, &xsg[cur ^ 1][q0 + 1][0]);
        }
        const int kb = c * BK;
#pragma unroll
        for (int g = 0; g < NGRAN; g += 2) {
            // 8 experts x 8 ks, wave-uniform addresses -> s_load_dwordx8 each
            const f32x8 w0 = *(const f32x8*)(wp + 0 * D_MODEL + kb + g * 4);
            const f32x8 w1 = *(const f32x8*)(wp + 1 * D_MODEL + kb + g * 4);
            const f32x8 w2 = *(const f32x8*)(wp + 2 * D_MODEL + kb + g * 4);
            const f32x8 w3 = *(const f32x8*)(wp + 3 * D_MODEL + kb + g * 4);
            const f32x8 w4 = *(const f32x8*)(wp + 4 * D_MODEL + kb + g * 4);
            const f32x8 w5 = *(const f32x8*)(wp + 5 * D_MODEL + kb + g * 4);
            const f32x8 w6 = *(const f32x8*)(wp + 6 * D_MODEL + kb + g * 4);
            const f32x8 w7 = *(const f32x8*)(wp + 7 * D_MODEL + kb + g * 4);
            // own row's 8 ks: two conflict-free b128 (lane i -> byte i*16)
            const float4 xa = xsg[cur][g][lane];
            const float4 xb = xsg[cur][g + 1][lane];
            ROW_FMA(0, w0) ROW_FMA(1, w1) ROW_FMA(2, w2) ROW_FMA(3, w3)
            ROW_FMA(4, w4) ROW_FMA(5, w5) ROW_FMA(6, w6) ROW_FMA(7, w7)
        }
        __syncthreads();  // all waves done reading buf cur; next stage done
    }

    // scatter logits to LDS: lane l holds row l, experts [8w, 8w+8)
    {
        float4 lo, hi;
        lo.x = acc[0]; lo.y = acc[1]; lo.z = acc[2]; lo.w = acc[3];
        hi.x = acc[4]; hi.y = acc[5]; hi.z = acc[6]; hi.w = acc[7];
        *(float4*)&logits[lane][w * 8]     = lo;
        *(float4*)&logits[lane][w * 8 + 4] = hi;
    }
    __syncthreads();

    // epilogue: one thread per row (wave 0), identical to verified baseline
    if (t < BM) {
        const int row = r0 + t;
        float m1 = -INFINITY, m2 = -INFINITY;
        int   e1 = 0, e2 = 0;
        for (int e = 0; e < NEXP; ++e) {
            const float l = logits[t][e] + bias[e];
            if (l > m1) { m2 = m1; e2 = e1; m1 = l; e1 = e; }
            else if (l > m2) { m2 = l; e2 = e; }
        }
        float z = 0.f;
        for (int e = 0; e < NEXP; ++e)
            z += expf(logits[t][e] + bias[e] - m1);
        const float p2    = expf(m2 - m1);
        const float denom = (1.f + p2) + 1e-8f * z;
        out[row * 2 + 0] = 1.f / denom;
        out[row * 2 + 1] = p2 / denom;
        float* oidx = out + 2 * NROWS;
        oidx[row * 2 + 0] = (float)e1;
        oidx[row * 2 + 1] = (float)e2;
    }
}

extern "C" void kernel_launch(void* const* d_in, const int* in_sizes, int n_in,
                              void* d_out, int out_size, void* d_ws, size_t ws_size,
                              hipStream_t stream) {
    const float* x    = (const float*)d_in[0];   // [32768, 2048]
    const float* gw   = (const float*)d_in[1];   // [64, 2048]
    const float* bias = (const float*)d_in[2];   // [64]
    float* out = (float*)d_out;                  // 131072 floats
    (void)in_sizes; (void)n_in; (void)out_size; (void)d_ws; (void)ws_size;

    dim3 grid(NROWS / BM);   // 512 blocks -> 2 blocks/CU, 16 waves/CU
    dim3 block(512);         // 8 waves
    router_kernel<<<grid, block, 0, stream>>>(x, gw, bias, out);
}